// Round 5
// baseline (1151.352 us; speedup 1.0000x reference)
//
#include <hip/hip_runtime.h>
#include <math.h>

#define EPSF 1e-8f
#define NSRC 1024
#define NTGT 1024
#define NTOT 2048
#define DIM  2048
#define NCLS 4

// ---------------- workspace layout (bytes) ----------------
constexpr size_t OFF_D2      = 0;                               // 2048*2048 f32
constexpr size_t OFF_WBUF    = (size_t)NTOT * NTOT * 4;         // 1024 f32
constexpr size_t OFF_NORMS   = OFF_WBUF + 1024 * 4;             // 2048 f32
constexpr size_t OFF_CLSOF   = OFF_NORMS + 2048 * 4;            // 2048 i32
constexpr size_t OFF_CIDX    = OFF_CLSOF + 2048 * 4;            // 4*2048 i32
constexpr size_t OFF_CCNT    = OFF_CIDX + 4 * 2048 * 4;         // 4 i32  <-- zero region starts here
constexpr size_t OFF_CNS     = OFF_CCNT + 16;                   // 4 i32
constexpr size_t OFF_CNT     = OFF_CNS + 16;                    // 4 i32
constexpr size_t OFF_LOSS2   = OFF_CNT + 16;                    // 2 f32
constexpr size_t OFF_SELBIN  = OFF_LOSS2 + 16;                  // 4 u32
constexpr size_t OFF_SELBASE = OFF_SELBIN + 16;                 // 4 u32
constexpr size_t OFF_INV2S   = OFF_SELBASE + 16;                // 4 f32
constexpr size_t OFF_SSUM    = OFF_INV2S + 16;                  // 4*5 f32 (ss, tt, st_both, Tss, Ttt)
constexpr size_t OFF_HIST    = ((OFF_SSUM + 80 + 255) / 256) * 256; // 4*65536 u32
constexpr size_t OFF_HIST2   = OFF_HIST + 4 * 65536 * 4;        // 4*65536 u32
constexpr size_t WS_END      = OFF_HIST2 + 4 * 65536 * 4;

__device__ __forceinline__ float waveReduceSum(float v) {
#pragma unroll
    for (int o = 32; o > 0; o >>= 1) v += __shfl_down(v, o, 64);
    return v;
}

// ---------------- row norms of comb ----------------
__global__ __launch_bounds__(256) void k_norms(const float* __restrict__ fs,
                                               const float* __restrict__ ft,
                                               float* __restrict__ norms) {
    int row = blockIdx.x;
    const float* src = row < NSRC ? fs + (size_t)row * DIM : ft + (size_t)(row - NSRC) * DIM;
    float s = 0.f;
    for (int k = threadIdx.x; k < DIM; k += 256) {
        float v = src[k];
        s = fmaf(v, v, s);
    }
    s = waveReduceSum(s);
    __shared__ float ls[4];
    int lane = threadIdx.x & 63, w = threadIdx.x >> 6;
    if (lane == 0) ls[w] = s;
    __syncthreads();
    if (threadIdx.x == 0) norms[row] = ls[0] + ls[1] + ls[2] + ls[3];
}

// ---------------- per-row stats: loss_cls, entropy, w, pseudo, class lists ----------------
__global__ __launch_bounds__(256) void k_rowstats(const float* __restrict__ logits_s,
                                                  const int* __restrict__ labels,
                                                  const float* __restrict__ logits_t,
                                                  float* __restrict__ wbuf,
                                                  int* __restrict__ clsof,
                                                  int* __restrict__ cidx,
                                                  int* __restrict__ ccnt,
                                                  int* __restrict__ cns,
                                                  int* __restrict__ cnt_,
                                                  float* __restrict__ loss2) {
    int tid = blockIdx.x * 256 + threadIdx.x;
    if (tid < NSRC) {
        float4 l = *(const float4*)(logits_s + (size_t)tid * 4);
        float m = fmaxf(fmaxf(l.x, l.y), fmaxf(l.z, l.w));
        float e0 = expf(l.x - m), e1 = expf(l.y - m), e2 = expf(l.z - m), e3 = expf(l.w - m);
        float lse = m + logf(e0 + e1 + e2 + e3);
        int lab = labels[tid];
        float lv = (lab == 0) ? l.x : (lab == 1) ? l.y : (lab == 2) ? l.z : l.w;
        atomicAdd(&loss2[0], lse - lv); // -log p[label]
        clsof[tid] = lab;
        atomicAdd(&cns[lab], 1);
        int pos = atomicAdd(&ccnt[lab], 1);
        cidx[lab * NTOT + pos] = tid;
    } else if (tid < NTOT) {
        int j = tid - NSRC;
        float4 l = *(const float4*)(logits_t + (size_t)j * 4);
        float m = fmaxf(fmaxf(l.x, l.y), fmaxf(l.z, l.w));
        float e0 = expf(l.x - m), e1 = expf(l.y - m), e2 = expf(l.z - m), e3 = expf(l.w - m);
        float s = e0 + e1 + e2 + e3;
        float p0 = e0 / s, p1 = e1 / s, p2 = e2 / s, p3 = e3 / s;
        float ent = 0.f;
        ent -= p0 * logf(p0 + EPSF);
        ent -= p1 * logf(p1 + EPSF);
        ent -= p2 * logf(p2 + EPSF);
        ent -= p3 * logf(p3 + EPSF);
        int bi = 0;
        float bv = l.x;
        if (l.y > bv) { bv = l.y; bi = 1; }
        if (l.z > bv) { bv = l.z; bi = 2; }
        if (l.w > bv) { bv = l.w; bi = 3; }
        float w = 1.f - ent / (logf(4.f) + EPSF);
        wbuf[j] = w;
        clsof[tid] = bi;
        atomicAdd(&loss2[1], ent);
        atomicAdd(&cnt_[bi], 1);
        int pos = atomicAdd(&ccnt[bi], 1);
        cidx[bi * NTOT + pos] = tid;
    }
}

// ---------------- D2 = ||xi||^2 + ||xj||^2 - 2 xi.xj (clamped at 0) ----------------
// Symmetric: only upper-triangular 64x64 blocks launched (528 of 1024);
// off-diagonal blocks write the tile AND its transpose. dot(xi,xj) uses the
// same k-order either way, so D2 is bitwise symmetric.
__global__ __launch_bounds__(256) void k_gemm_d2(const float* __restrict__ fs,
                                                 const float* __restrict__ ft,
                                                 const float* __restrict__ norms,
                                                 float* __restrict__ D2) {
    __shared__ float As[16][64];
    __shared__ float Bs[16][64];
    int t = threadIdx.x;
    // decode blockIdx.x (0..527) -> (by, bx) with by <= bx, 32 block-cols
    int p = blockIdx.x, by = 0;
    while (p >= 32 - by) { p -= 32 - by; ++by; }
    int bx = by + p;
    int rb = by * 64, cb = bx * 64;
    int tx = t & 15, ty = t >> 4;
    float acc[4][4] = {};
    int lm = t >> 2;            // 0..63 (tile row)
    int lk = (t & 3) * 4;       // 0,4,8,12 (k offset)
    int arow = rb + lm, brow = cb + lm;
    const float* asrc = arow < NSRC ? fs + (size_t)arow * DIM : ft + (size_t)(arow - NSRC) * DIM;
    const float* bsrc = brow < NSRC ? fs + (size_t)brow * DIM : ft + (size_t)(brow - NSRC) * DIM;

    for (int k0 = 0; k0 < DIM; k0 += 16) {
        float4 av = *(const float4*)(asrc + k0 + lk);
        float4 bv = *(const float4*)(bsrc + k0 + lk);
        __syncthreads();
        As[lk + 0][lm] = av.x; As[lk + 1][lm] = av.y; As[lk + 2][lm] = av.z; As[lk + 3][lm] = av.w;
        Bs[lk + 0][lm] = bv.x; Bs[lk + 1][lm] = bv.y; Bs[lk + 2][lm] = bv.z; Bs[lk + 3][lm] = bv.w;
        __syncthreads();
#pragma unroll
        for (int k = 0; k < 16; ++k) {
            float4 a = *(const float4*)&As[k][ty * 4];
            float4 b = *(const float4*)&Bs[k][tx * 4];
            acc[0][0] = fmaf(a.x, b.x, acc[0][0]);
            acc[0][1] = fmaf(a.x, b.y, acc[0][1]);
            acc[0][2] = fmaf(a.x, b.z, acc[0][2]);
            acc[0][3] = fmaf(a.x, b.w, acc[0][3]);
            acc[1][0] = fmaf(a.y, b.x, acc[1][0]);
            acc[1][1] = fmaf(a.y, b.y, acc[1][1]);
            acc[1][2] = fmaf(a.y, b.z, acc[1][2]);
            acc[1][3] = fmaf(a.y, b.w, acc[1][3]);
            acc[2][0] = fmaf(a.z, b.x, acc[2][0]);
            acc[2][1] = fmaf(a.z, b.y, acc[2][1]);
            acc[2][2] = fmaf(a.z, b.z, acc[2][2]);
            acc[2][3] = fmaf(a.z, b.w, acc[2][3]);
            acc[3][0] = fmaf(a.w, b.x, acc[3][0]);
            acc[3][1] = fmaf(a.w, b.y, acc[3][1]);
            acc[3][2] = fmaf(a.w, b.z, acc[3][2]);
            acc[3][3] = fmaf(a.w, b.w, acc[3][3]);
        }
    }
    bool offdiag = (bx != by);
#pragma unroll
    for (int i = 0; i < 4; ++i) {
        int gi = rb + ty * 4 + i;
        float ni = norms[gi];
#pragma unroll
        for (int j = 0; j < 4; ++j) {
            int gj = cb + tx * 4 + j;
            float d = fmaxf(ni + norms[gj] - 2.f * acc[i][j], 0.f);
            D2[(size_t)gi * NTOT + gj] = d;
            if (offdiag) D2[(size_t)gj * NTOT + gi] = d;
        }
    }
}

// ---------------- pair histograms for exact lower-median selection ----------------
// pass 1: histogram of high 16 bits of D2 bit pattern over all class pairs (a<b).
// pass 2: histogram of low 16 bits restricted to the selected high bin.
__global__ __launch_bounds__(256) void k_pairhist(const float* __restrict__ D2,
                                                  const int* __restrict__ cidx,
                                                  const int* __restrict__ ccnt,
                                                  unsigned* __restrict__ hist,
                                                  const unsigned* __restrict__ selbin,
                                                  int pass) {
    int c = blockIdx.y;
    int n = ccnt[c];
    if (n < 2) return;
    const int* idx = cidx + c * NTOT;
    unsigned* h = hist + c * 65536;
    unsigned sb = (pass == 2) ? selbin[c] : 0u;
    int total = n * n;
    int stride = gridDim.x * blockDim.x;
    for (int p = blockIdx.x * blockDim.x + threadIdx.x; p < total; p += stride) {
        int a = p / n, b = p - a * n;
        if (a >= b) continue;
        float v = D2[(size_t)idx[a] * NTOT + idx[b]];
        unsigned bits = __float_as_uint(v);
        if (pass == 1) atomicAdd(h + (bits >> 16), 1u);
        else if ((bits >> 16) == sb) atomicAdd(h + (bits & 0xFFFFu), 1u);
    }
}

// ---------------- select k-th within a 65536-bin histogram ----------------
__global__ __launch_bounds__(256) void k_select(const unsigned* __restrict__ hist,
                                                const int* __restrict__ ccnt,
                                                unsigned* __restrict__ selbin,
                                                unsigned* __restrict__ selbase,
                                                float* __restrict__ inv2s,
                                                int pass) {
    int c = blockIdx.x;
    int t = threadIdx.x;
    long long n = ccnt[c];
    long long P = n * (n - 1) / 2;
    if (P == 0) {
        if (t == 0 && pass == 2) {
            float med = 1.0f;
            inv2s[c] = 1.f / (2.f * (med + 1e-6f) + EPSF);
        }
        return;
    }
    unsigned target = (unsigned)((P - 1) / 2) + 1u;
    if (pass == 2) target -= selbase[c];
    const unsigned* h = hist + c * 65536;

    unsigned local = 0;
    int b0 = t * 256;
    for (int b = b0; b < b0 + 256; ++b) local += h[b];
    __shared__ unsigned ls[256];
    __shared__ unsigned sbin;
    ls[t] = local;
    if (t == 0) sbin = 0xFFFFFFFFu;
    __syncthreads();
    unsigned prefix = 0;
    for (int i = 0; i < t; ++i) prefix += ls[i];

    unsigned cum = prefix;
    unsigned fbin = 0xFFFFFFFFu, fbase = 0;
    for (int b = b0; b < b0 + 256; ++b) {
        unsigned hv = h[b];
        if (cum + hv >= target) { fbin = (unsigned)b; fbase = cum; break; }
        cum += hv;
    }
    if (fbin != 0xFFFFFFFFu) atomicMin(&sbin, fbin);
    __syncthreads();
    if (fbin == sbin && fbin != 0xFFFFFFFFu) {
        if (pass == 1) {
            selbin[c] = fbin;
            selbase[c] = fbase;
        } else {
            unsigned bits = (selbin[c] << 16) | fbin;
            float med = __uint_as_float(bits);
            inv2s[c] = 1.f / (2.f * (med + 1e-6f) + EPSF);
        }
    }
}

// ---------------- masked kernel-matrix sums per class ----------------
// S[c][0]=sum Kss^2, [1]=sum Ktt^2 (w-weighted), [2]=sum over both st orientations,
// [3]=tr(Kss), [4]=tr(Ktt)
__global__ __launch_bounds__(256) void k_sums(const float* __restrict__ D2,
                                              const int* __restrict__ clsof,
                                              const float* __restrict__ wbuf,
                                              const float* __restrict__ inv2s,
                                              float* __restrict__ S) {
    int c = blockIdx.y;
    float is2 = inv2s[c];
    float ss = 0.f, tt = 0.f, st = 0.f, trs = 0.f, trt = 0.f;
    int stride = gridDim.x * blockDim.x;
    for (int e = blockIdx.x * blockDim.x + threadIdx.x; e < NTOT * NTOT; e += stride) {
        int i = e >> 11, j = e & (NTOT - 1);
        if (clsof[i] != c || clsof[j] != c) continue;
        float d = D2[e];
        float Kv = expf(-d * is2);
        float K2 = Kv * Kv;
        bool si = i < NSRC, sj = j < NSRC;
        if (si && sj) {
            ss += K2;
        } else if (!si && !sj) {
            float ww = wbuf[i - NSRC] * wbuf[j - NSRC];
            tt += ww * ww * K2;
        } else {
            st += K2;
        }
        if (i == j) {
            if (si) trs += Kv;
            else {
                float w = wbuf[i - NSRC];
                trt += w * w * Kv;
            }
        }
    }
    ss = waveReduceSum(ss);
    tt = waveReduceSum(tt);
    st = waveReduceSum(st);
    trs = waveReduceSum(trs);
    trt = waveReduceSum(trt);
    if ((threadIdx.x & 63) == 0) {
        atomicAdd(&S[c * 5 + 0], ss);
        atomicAdd(&S[c * 5 + 1], tt);
        atomicAdd(&S[c * 5 + 2], st);
        atomicAdd(&S[c * 5 + 3], trs);
        atomicAdd(&S[c * 5 + 4], trt);
    }
}

// ---------------- final combine ----------------
__global__ void k_final(const float* __restrict__ S,
                        const int* __restrict__ cns,
                        const int* __restrict__ cnt_,
                        const float* __restrict__ loss2,
                        float* __restrict__ out) {
    if (threadIdx.x != 0 || blockIdx.x != 0) return;
    float csum = 0.f;
    int nv = 0;
    for (int c = 0; c < NCLS; ++c) {
        float Sss = S[c * 5 + 0], Stt = S[c * 5 + 1], Sst2 = S[c * 5 + 2];
        float Tss = S[c * 5 + 3], Ttt = S[c * 5 + 4];
        float trs = Tss + EPSF, trt = Ttt + EPSF, trm = Tss + Ttt + EPSF;
        float h2s = -log2f(Sss / (trs * trs) + EPSF);
        float h2t = -log2f(Stt / (trt * trt) + EPSF);
        float h2m = -log2f((Sss + Stt + Sst2) / (trm * trm) + EPSF);
        if (cns[c] >= 2 && cnt_[c] >= 2) {
            csum += h2m - 0.5f * (h2s + h2t);
            nv++;
        }
    }
    float creda = (nv > 0) ? csum / (float)nv : 0.f;
    out[0] = loss2[0] * (1.f / 1024.f) + creda + 0.1f * (loss2[1] * (1.f / 1024.f));
}

extern "C" void kernel_launch(void* const* d_in, const int* in_sizes, int n_in,
                              void* d_out, int out_size, void* d_ws, size_t ws_size,
                              hipStream_t stream) {
    const float* fs  = (const float*)d_in[0];
    const float* ls  = (const float*)d_in[1];
    const int*   lab = (const int*)d_in[2];
    const float* ft  = (const float*)d_in[3];
    const float* lt  = (const float*)d_in[4];
    float* out = (float*)d_out;
    char* ws = (char*)d_ws;

    float*    D2      = (float*)(ws + OFF_D2);
    float*    wbuf    = (float*)(ws + OFF_WBUF);
    float*    norms   = (float*)(ws + OFF_NORMS);
    int*      clsof   = (int*)(ws + OFF_CLSOF);
    int*      cidx    = (int*)(ws + OFF_CIDX);
    int*      ccnt    = (int*)(ws + OFF_CCNT);
    int*      cns     = (int*)(ws + OFF_CNS);
    int*      cnt_    = (int*)(ws + OFF_CNT);
    float*    loss2   = (float*)(ws + OFF_LOSS2);
    unsigned* selbin  = (unsigned*)(ws + OFF_SELBIN);
    unsigned* selbase = (unsigned*)(ws + OFF_SELBASE);
    float*    inv2s   = (float*)(ws + OFF_INV2S);
    float*    Ssum    = (float*)(ws + OFF_SSUM);
    unsigned* hist    = (unsigned*)(ws + OFF_HIST);
    unsigned* hist2   = (unsigned*)(ws + OFF_HIST2);

    // zero the counters/accumulators/histograms (ws is poisoned 0xAA each call)
    hipMemsetAsync(ws + OFF_CCNT, 0, WS_END - OFF_CCNT, stream);

    k_norms<<<NTOT, 256, 0, stream>>>(fs, ft, norms);
    k_rowstats<<<NTOT / 256, 256, 0, stream>>>(ls, lab, lt, wbuf, clsof, cidx, ccnt, cns, cnt_, loss2);
    k_gemm_d2<<<528, 256, 0, stream>>>(fs, ft, norms, D2);
    k_pairhist<<<dim3(128, NCLS), 256, 0, stream>>>(D2, cidx, ccnt, hist, selbin, 1);
    k_select<<<NCLS, 256, 0, stream>>>(hist, ccnt, selbin, selbase, inv2s, 1);
    k_pairhist<<<dim3(128, NCLS), 256, 0, stream>>>(D2, cidx, ccnt, hist2, selbin, 2);
    k_select<<<NCLS, 256, 0, stream>>>(hist2, ccnt, selbin, selbase, inv2s, 2);
    k_sums<<<dim3(512, NCLS), 256, 0, stream>>>(D2, clsof, wbuf, inv2s, Ssum);
    k_final<<<1, 64, 0, stream>>>(Ssum, cns, cnt_, loss2, out);
}

// Round 9
// 597.712 us; speedup vs baseline: 1.9263x; 1.9263x over previous
//
#include <hip/hip_runtime.h>
#include <math.h>

#define EPSF 1e-8f
#define NSRC 1024
#define NTGT 1024
#define NTOT 2048
#define DIM  2048
#define NCLS 4

typedef __attribute__((ext_vector_type(8))) short short8v;
typedef __attribute__((ext_vector_type(4))) float f32x4;

// ---------------- workspace layout (bytes) ----------------
constexpr size_t OFF_D2      = 0;                               // 2048*2048 f32
constexpr size_t OFF_WBUF    = (size_t)NTOT * NTOT * 4;         // 1024 f32
constexpr size_t OFF_NORMS   = OFF_WBUF + 1024 * 4;             // 2048 f32
constexpr size_t OFF_CLSOF   = OFF_NORMS + 2048 * 4;            // 2048 i32
constexpr size_t OFF_CIDX    = OFF_CLSOF + 2048 * 4;            // 4*2048 i32
constexpr size_t OFF_CCNT    = OFF_CIDX + 4 * 2048 * 4;         // 4 i32  <-- zero region starts here
constexpr size_t OFF_CNS     = OFF_CCNT + 16;                   // 4 i32
constexpr size_t OFF_CNT     = OFF_CNS + 16;                    // 4 i32
constexpr size_t OFF_LOSS2   = OFF_CNT + 16;                    // 2 f32
constexpr size_t OFF_SELBIN  = OFF_LOSS2 + 16;                  // 4 u32
constexpr size_t OFF_SELBASE = OFF_SELBIN + 16;                 // 4 u32
constexpr size_t OFF_INV2S   = OFF_SELBASE + 16;                // 4 f32
constexpr size_t OFF_SSUM    = OFF_INV2S + 16;                  // 4*5 f32 (ss, tt, st_both, Tss, Ttt)
constexpr size_t OFF_HIST    = ((OFF_SSUM + 80 + 255) / 256) * 256; // 4*65536 u32
constexpr size_t OFF_HIST2   = OFF_HIST + 4 * 65536 * 4;        // 4*65536 u32
constexpr size_t WS_END      = OFF_HIST2 + 4 * 65536 * 4;

__device__ __forceinline__ float waveReduceSum(float v) {
#pragma unroll
    for (int o = 32; o > 0; o >>= 1) v += __shfl_down(v, o, 64);
    return v;
}

// round-to-nearest-even f32 -> bf16 (as raw short)
__device__ __forceinline__ short bf16_rne(float x) {
    unsigned u = __float_as_uint(x);
    unsigned r = (u + 0x7FFFu + ((u >> 16) & 1u)) >> 16;
    return (short)r;
}
__device__ __forceinline__ float bf16_to_f32(short h) {
    return __uint_as_float(((unsigned)(unsigned short)h) << 16);
}

// ---------------- row norms of comb ----------------
__global__ __launch_bounds__(256) void k_norms(const float* __restrict__ fs,
                                               const float* __restrict__ ft,
                                               float* __restrict__ norms) {
    int row = blockIdx.x;
    const float* src = row < NSRC ? fs + (size_t)row * DIM : ft + (size_t)(row - NSRC) * DIM;
    float s = 0.f;
    for (int k = threadIdx.x; k < DIM; k += 256) {
        float v = src[k];
        s = fmaf(v, v, s);
    }
    s = waveReduceSum(s);
    __shared__ float ls[4];
    int lane = threadIdx.x & 63, w = threadIdx.x >> 6;
    if (lane == 0) ls[w] = s;
    __syncthreads();
    if (threadIdx.x == 0) norms[row] = ls[0] + ls[1] + ls[2] + ls[3];
}

// ---------------- per-row stats: loss_cls, entropy, w, pseudo, class lists ----------------
__global__ __launch_bounds__(256) void k_rowstats(const float* __restrict__ logits_s,
                                                  const int* __restrict__ labels,
                                                  const float* __restrict__ logits_t,
                                                  float* __restrict__ wbuf,
                                                  int* __restrict__ clsof,
                                                  int* __restrict__ cidx,
                                                  int* __restrict__ ccnt,
                                                  int* __restrict__ cns,
                                                  int* __restrict__ cnt_,
                                                  float* __restrict__ loss2) {
    int tid = blockIdx.x * 256 + threadIdx.x;
    if (tid < NSRC) {
        float4 l = *(const float4*)(logits_s + (size_t)tid * 4);
        float m = fmaxf(fmaxf(l.x, l.y), fmaxf(l.z, l.w));
        float e0 = expf(l.x - m), e1 = expf(l.y - m), e2 = expf(l.z - m), e3 = expf(l.w - m);
        float lse = m + logf(e0 + e1 + e2 + e3);
        int lab = labels[tid];
        float lv = (lab == 0) ? l.x : (lab == 1) ? l.y : (lab == 2) ? l.z : l.w;
        atomicAdd(&loss2[0], lse - lv); // -log p[label]
        clsof[tid] = lab;
        atomicAdd(&cns[lab], 1);
        int pos = atomicAdd(&ccnt[lab], 1);
        cidx[lab * NTOT + pos] = tid;
    } else if (tid < NTOT) {
        int j = tid - NSRC;
        float4 l = *(const float4*)(logits_t + (size_t)j * 4);
        float m = fmaxf(fmaxf(l.x, l.y), fmaxf(l.z, l.w));
        float e0 = expf(l.x - m), e1 = expf(l.y - m), e2 = expf(l.z - m), e3 = expf(l.w - m);
        float s = e0 + e1 + e2 + e3;
        float p0 = e0 / s, p1 = e1 / s, p2 = e2 / s, p3 = e3 / s;
        float ent = 0.f;
        ent -= p0 * logf(p0 + EPSF);
        ent -= p1 * logf(p1 + EPSF);
        ent -= p2 * logf(p2 + EPSF);
        ent -= p3 * logf(p3 + EPSF);
        int bi = 0;
        float bv = l.x;
        if (l.y > bv) { bv = l.y; bi = 1; }
        if (l.z > bv) { bv = l.z; bi = 2; }
        if (l.w > bv) { bv = l.w; bi = 3; }
        float w = 1.f - ent / (logf(4.f) + EPSF);
        wbuf[j] = w;
        clsof[tid] = bi;
        atomicAdd(&loss2[1], ent);
        atomicAdd(&cnt_[bi], 1);
        int pos = atomicAdd(&ccnt[bi], 1);
        cidx[bi * NTOT + pos] = tid;
    }
}

// ---------------- D2 via split-bf16 MFMA Gram ----------------
// comb row a = hi + lo (bf16 RNE split); dot ~= hi*hi + hi*lo + lo*hi (lo*lo
// dropped, ~1e-6 relative on D2). Gram symmetry makes the MFMA A/B k-layout
// guess self-cancelling (both operands loaded with the identical lane pattern)
// and the C/D orientation irrelevant (off-diag blocks write both (i,j),(j,i);
// diag blocks are symmetric).
// Tile 64x64, BK=32, 4 waves; each wave owns a 32x32 quadrant (2x2 MFMA frags).
__global__ __launch_bounds__(256) void k_gemm_d2(const float* __restrict__ fs,
                                                 const float* __restrict__ ft,
                                                 const float* __restrict__ norms,
                                                 float* __restrict__ D2) {
    // LDS: [64 rows][40 bf16] (pad 32->40: 80B stride = 16B aligned, 2-way bank alias = free)
    __shared__ short Ah[64][40], Al[64][40], Bh[64][40], Bl[64][40];
    int t = threadIdx.x;
    // decode blockIdx.x (0..527) -> (by, bx) with by <= bx, 32 block-cols
    int p = blockIdx.x, by = 0;
    while (p >= 32 - by) { p -= 32 - by; ++by; }
    int bx = by + p;
    int rb = by * 64, cb = bx * 64;

    // staging assignment: thread t loads row (t>>2), f32 cols (t&3)*8 .. +7
    int sr = t >> 2, sc = (t & 3) * 8;
    int arow = rb + sr, brow = cb + sr;
    const float* asrc = (arow < NSRC ? fs + (size_t)arow * DIM : ft + (size_t)(arow - NSRC) * DIM) + sc;
    const float* bsrc = (brow < NSRC ? fs + (size_t)brow * DIM : ft + (size_t)(brow - NSRC) * DIM) + sc;

    int lane = t & 63;
    int q = lane >> 4;        // k-quadrant 0..3
    int lr = lane & 15;       // row/col within fragment
    int wid = t >> 6;
    int wr = wid >> 1, wc = wid & 1;   // wave quadrant of 64x64 tile

    f32x4 acc[2][2] = {};

    for (int k0 = 0; k0 < DIM; k0 += 32) {
        __syncthreads();  // previous iteration's frag reads done
        // ---- stage + convert f32 -> hi/lo bf16 ----
        {
            float4 v0 = *(const float4*)(asrc + k0);
            float4 v1 = *(const float4*)(asrc + k0 + 4);
            short8v h, l;
            float vv[8] = {v0.x, v0.y, v0.z, v0.w, v1.x, v1.y, v1.z, v1.w};
#pragma unroll
            for (int i = 0; i < 8; ++i) {
                short hb = bf16_rne(vv[i]);
                h[i] = hb;
                l[i] = bf16_rne(vv[i] - bf16_to_f32(hb));
            }
            *(short8v*)&Ah[sr][sc] = h;
            *(short8v*)&Al[sr][sc] = l;
            v0 = *(const float4*)(bsrc + k0);
            v1 = *(const float4*)(bsrc + k0 + 4);
            float uu[8] = {v0.x, v0.y, v0.z, v0.w, v1.x, v1.y, v1.z, v1.w};
#pragma unroll
            for (int i = 0; i < 8; ++i) {
                short hb = bf16_rne(uu[i]);
                h[i] = hb;
                l[i] = bf16_rne(uu[i] - bf16_to_f32(hb));
            }
            *(short8v*)&Bh[sr][sc] = h;
            *(short8v*)&Bl[sr][sc] = l;
        }
        __syncthreads();
        // ---- fragments + MFMA ----
        short8v ah[2], al[2], bh[2], bl[2];
#pragma unroll
        for (int mi = 0; mi < 2; ++mi) {
            int r = wr * 32 + mi * 16 + lr;
            ah[mi] = *(short8v*)&Ah[r][q * 8];
            al[mi] = *(short8v*)&Al[r][q * 8];
        }
#pragma unroll
        for (int ni = 0; ni < 2; ++ni) {
            int r = wc * 32 + ni * 16 + lr;
            bh[ni] = *(short8v*)&Bh[r][q * 8];
            bl[ni] = *(short8v*)&Bl[r][q * 8];
        }
#pragma unroll
        for (int mi = 0; mi < 2; ++mi)
#pragma unroll
            for (int ni = 0; ni < 2; ++ni) {
                acc[mi][ni] = __builtin_amdgcn_mfma_f32_16x16x32_bf16(ah[mi], bh[ni], acc[mi][ni], 0, 0, 0);
                acc[mi][ni] = __builtin_amdgcn_mfma_f32_16x16x32_bf16(ah[mi], bl[ni], acc[mi][ni], 0, 0, 0);
                acc[mi][ni] = __builtin_amdgcn_mfma_f32_16x16x32_bf16(al[mi], bh[ni], acc[mi][ni], 0, 0, 0);
            }
    }

    // ---- epilogue: d = n_i + n_j - 2*dot, clamp, write (+transpose if offdiag) ----
    bool offdiag = (bx != by);
#pragma unroll
    for (int mi = 0; mi < 2; ++mi)
#pragma unroll
        for (int ni = 0; ni < 2; ++ni)
#pragma unroll
            for (int i = 0; i < 4; ++i) {
                int gi = rb + wr * 32 + mi * 16 + q * 4 + i;
                int gj = cb + wc * 32 + ni * 16 + lr;
                float d = fmaxf(norms[gi] + norms[gj] - 2.f * acc[mi][ni][i], 0.f);
                D2[(size_t)gi * NTOT + gj] = d;
                if (offdiag) D2[(size_t)gj * NTOT + gi] = d;
            }
}

// ---------------- pair histograms for exact lower-median selection ----------------
// pass 1: histogram of high 16 bits of D2 bit pattern over all class pairs (a<b).
//   D2 values cluster -> wave-aggregate with ballot: one atomic per distinct bin.
// pass 2: histogram of low 16 bits restricted to the selected high bin.
__global__ __launch_bounds__(256) void k_pairhist(const float* __restrict__ D2,
                                                  const int* __restrict__ cidx,
                                                  const int* __restrict__ ccnt,
                                                  unsigned* __restrict__ hist,
                                                  const unsigned* __restrict__ selbin,
                                                  int pass) {
    int c = blockIdx.y;
    int n = ccnt[c];
    if (n < 2) return;
    const int* idx = cidx + c * NTOT;
    unsigned* h = hist + c * 65536;
    int total = n * n;
    int stride = gridDim.x * blockDim.x;
    int lane = threadIdx.x & 63;

    if (pass == 1) {
        for (int p = blockIdx.x * blockDim.x + threadIdx.x;; p += stride) {
            bool inb = p < total;
            if (!__any(inb)) break;
            unsigned bin = 0;
            bool want = false;
            if (inb) {
                int a = p / n, b = p - a * n;
                if (a < b) {
                    float v = D2[(size_t)idx[a] * NTOT + idx[b]];
                    bin = __float_as_uint(v) >> 16;
                    want = true;
                }
            }
            while (__any(want)) {
                unsigned long long m = __ballot(want);
                int leader = __ffsll((long long)m) - 1;
                unsigned lbin = __shfl(bin, leader, 64);
                bool same = want && (bin == lbin);
                unsigned long long sm = __ballot(same);
                if (lane == leader) atomicAdd(h + lbin, (unsigned)__popcll(sm));
                want = want && !same;
            }
        }
    } else {
        unsigned sb = selbin[c];
        for (int p = blockIdx.x * blockDim.x + threadIdx.x; p < total; p += stride) {
            int a = p / n, b = p - a * n;
            if (a >= b) continue;
            float v = D2[(size_t)idx[a] * NTOT + idx[b]];
            unsigned bits = __float_as_uint(v);
            if ((bits >> 16) == sb) atomicAdd(h + (bits & 0xFFFFu), 1u);
        }
    }
}

// ---------------- select k-th within a 65536-bin histogram ----------------
__global__ __launch_bounds__(256) void k_select(const unsigned* __restrict__ hist,
                                                const int* __restrict__ ccnt,
                                                unsigned* __restrict__ selbin,
                                                unsigned* __restrict__ selbase,
                                                float* __restrict__ inv2s,
                                                int pass) {
    int c = blockIdx.x;
    int t = threadIdx.x;
    long long n = ccnt[c];
    long long P = n * (n - 1) / 2;
    if (P == 0) {
        if (t == 0 && pass == 2) {
            float med = 1.0f;
            inv2s[c] = 1.f / (2.f * (med + 1e-6f) + EPSF);
        }
        return;
    }
    unsigned target = (unsigned)((P - 1) / 2) + 1u;
    if (pass == 2) target -= selbase[c];
    const unsigned* h = hist + c * 65536;

    unsigned local = 0;
    int b0 = t * 256;
    for (int b = b0; b < b0 + 256; ++b) local += h[b];
    __shared__ unsigned ls[256];
    __shared__ unsigned sbin;
    ls[t] = local;
    if (t == 0) sbin = 0xFFFFFFFFu;
    __syncthreads();
    unsigned prefix = 0;
    for (int i = 0; i < t; ++i) prefix += ls[i];

    unsigned cum = prefix;
    unsigned fbin = 0xFFFFFFFFu, fbase = 0;
    for (int b = b0; b < b0 + 256; ++b) {
        unsigned hv = h[b];
        if (cum + hv >= target) { fbin = (unsigned)b; fbase = cum; break; }
        cum += hv;
    }
    if (fbin != 0xFFFFFFFFu) atomicMin(&sbin, fbin);
    __syncthreads();
    if (fbin == sbin && fbin != 0xFFFFFFFFu) {
        if (pass == 1) {
            selbin[c] = fbin;
            selbase[c] = fbase;
        } else {
            unsigned bits = (selbin[c] << 16) | fbin;
            float med = __uint_as_float(bits);
            inv2s[c] = 1.f / (2.f * (med + 1e-6f) + EPSF);
        }
    }
}

// ---------------- masked kernel-matrix sums per class (gather over class lists) --
__global__ __launch_bounds__(256) void k_sums(const float* __restrict__ D2,
                                              const int* __restrict__ cidx,
                                              const int* __restrict__ ccnt,
                                              const float* __restrict__ wbuf,
                                              const float* __restrict__ inv2s,
                                              float* __restrict__ S) {
    int c = blockIdx.y;
    int n = ccnt[c];
    if (n == 0) return;
    const int* idx = cidx + c * NTOT;
    float is2 = inv2s[c];
    float ss = 0.f, tt = 0.f, st = 0.f, trs = 0.f, trt = 0.f;
    for (int a = blockIdx.x; a < n; a += gridDim.x) {
        int i = idx[a];
        bool si = i < NSRC;
        float wi = si ? 1.f : wbuf[i - NSRC];
        const float* drow = D2 + (size_t)i * NTOT;
        for (int b = threadIdx.x; b < n; b += 256) {
            int j = idx[b];
            float d = drow[j];
            float Kv = expf(-d * is2);
            float K2 = Kv * Kv;
            bool sj = j < NSRC;
            if (si && sj) {
                ss += K2;
            } else if (!si && !sj) {
                float ww = wi * wbuf[j - NSRC];
                tt += ww * ww * K2;
            } else {
                st += K2;
            }
            if (i == j) {
                if (si) trs += Kv;
                else trt += wi * wi * Kv;
            }
        }
    }
    ss = waveReduceSum(ss);
    tt = waveReduceSum(tt);
    st = waveReduceSum(st);
    trs = waveReduceSum(trs);
    trt = waveReduceSum(trt);
    __shared__ float red[4][5];
    int lane = threadIdx.x & 63, w = threadIdx.x >> 6;
    if (lane == 0) { red[w][0] = ss; red[w][1] = tt; red[w][2] = st; red[w][3] = trs; red[w][4] = trt; }
    __syncthreads();
    if (threadIdx.x < 5) {
        float v = red[0][threadIdx.x] + red[1][threadIdx.x] + red[2][threadIdx.x] + red[3][threadIdx.x];
        atomicAdd(&S[c * 5 + threadIdx.x], v);
    }
}

// ---------------- final combine ----------------
__global__ void k_final(const float* __restrict__ S,
                        const int* __restrict__ cns,
                        const int* __restrict__ cnt_,
                        const float* __restrict__ loss2,
                        float* __restrict__ out) {
    if (threadIdx.x != 0 || blockIdx.x != 0) return;
    float csum = 0.f;
    int nv = 0;
    for (int c = 0; c < NCLS; ++c) {
        float Sss = S[c * 5 + 0], Stt = S[c * 5 + 1], Sst2 = S[c * 5 + 2];
        float Tss = S[c * 5 + 3], Ttt = S[c * 5 + 4];
        float trs = Tss + EPSF, trt = Ttt + EPSF, trm = Tss + Ttt + EPSF;
        float h2s = -log2f(Sss / (trs * trs) + EPSF);
        float h2t = -log2f(Stt / (trt * trt) + EPSF);
        float h2m = -log2f((Sss + Stt + Sst2) / (trm * trm) + EPSF);
        if (cns[c] >= 2 && cnt_[c] >= 2) {
            csum += h2m - 0.5f * (h2s + h2t);
            nv++;
        }
    }
    float creda = (nv > 0) ? csum / (float)nv : 0.f;
    out[0] = loss2[0] * (1.f / 1024.f) + creda + 0.1f * (loss2[1] * (1.f / 1024.f));
}

extern "C" void kernel_launch(void* const* d_in, const int* in_sizes, int n_in,
                              void* d_out, int out_size, void* d_ws, size_t ws_size,
                              hipStream_t stream) {
    const float* fs  = (const float*)d_in[0];
    const float* ls  = (const float*)d_in[1];
    const int*   lab = (const int*)d_in[2];
    const float* ft  = (const float*)d_in[3];
    const float* lt  = (const float*)d_in[4];
    float* out = (float*)d_out;
    char* ws = (char*)d_ws;

    float*    D2      = (float*)(ws + OFF_D2);
    float*    wbuf    = (float*)(ws + OFF_WBUF);
    float*    norms   = (float*)(ws + OFF_NORMS);
    int*      clsof   = (int*)(ws + OFF_CLSOF);
    int*      cidx    = (int*)(ws + OFF_CIDX);
    int*      ccnt    = (int*)(ws + OFF_CCNT);
    int*      cns     = (int*)(ws + OFF_CNS);
    int*      cnt_    = (int*)(ws + OFF_CNT);
    float*    loss2   = (float*)(ws + OFF_LOSS2);
    unsigned* selbin  = (unsigned*)(ws + OFF_SELBIN);
    unsigned* selbase = (unsigned*)(ws + OFF_SELBASE);
    float*    inv2s   = (float*)(ws + OFF_INV2S);
    float*    Ssum    = (float*)(ws + OFF_SSUM);
    unsigned* hist    = (unsigned*)(ws + OFF_HIST);
    unsigned* hist2   = (unsigned*)(ws + OFF_HIST2);

    // zero the counters/accumulators/histograms (ws is poisoned 0xAA each call)
    hipMemsetAsync(ws + OFF_CCNT, 0, WS_END - OFF_CCNT, stream);

    k_norms<<<NTOT, 256, 0, stream>>>(fs, ft, norms);
    k_rowstats<<<NTOT / 256, 256, 0, stream>>>(ls, lab, lt, wbuf, clsof, cidx, ccnt, cns, cnt_, loss2);
    k_gemm_d2<<<528, 256, 0, stream>>>(fs, ft, norms, D2);
    k_pairhist<<<dim3(128, NCLS), 256, 0, stream>>>(D2, cidx, ccnt, hist, selbin, 1);
    k_select<<<NCLS, 256, 0, stream>>>(hist, ccnt, selbin, selbase, inv2s, 1);
    k_pairhist<<<dim3(128, NCLS), 256, 0, stream>>>(D2, cidx, ccnt, hist2, selbin, 2);
    k_select<<<NCLS, 256, 0, stream>>>(hist2, ccnt, selbin, selbase, inv2s, 2);
    k_sums<<<dim3(64, NCLS), 256, 0, stream>>>(D2, cidx, ccnt, wbuf, inv2s, Ssum);
    k_final<<<1, 64, 0, stream>>>(Ssum, cns, cnt_, loss2, out);
}

// Round 10
// 282.864 us; speedup vs baseline: 4.0703x; 2.1131x over previous
//
#include <hip/hip_runtime.h>
#include <math.h>

#define EPSF 1e-8f
#define NSRC 1024
#define NTGT 1024
#define NTOT 2048
#define DIM  2048
#define NCLS 4

typedef __attribute__((ext_vector_type(8))) short short8v;
typedef __attribute__((ext_vector_type(4))) float f32x4;

// ---------------- workspace layout (bytes) ----------------
constexpr size_t OFF_D2      = 0;                               // 2048*2048 f32
constexpr size_t OFF_WBUF    = (size_t)NTOT * NTOT * 4;         // 1024 f32
constexpr size_t OFF_NORMS   = OFF_WBUF + 1024 * 4;             // 2048 f32
constexpr size_t OFF_CLSOF   = OFF_NORMS + 2048 * 4;            // 2048 i32
constexpr size_t OFF_CIDX    = OFF_CLSOF + 2048 * 4;            // 4*2048 i32
constexpr size_t OFF_CCNT    = OFF_CIDX + 4 * 2048 * 4;         // 4 i32  <-- zero region starts here
constexpr size_t OFF_CNS     = OFF_CCNT + 16;                   // 4 i32
constexpr size_t OFF_CNT     = OFF_CNS + 16;                    // 4 i32
constexpr size_t OFF_LOSS2   = OFF_CNT + 16;                    // 2 f32
constexpr size_t OFF_SEL1    = OFF_LOSS2 + 16;                  // 4 u32
constexpr size_t OFF_SEL2    = OFF_SEL1 + 16;                   // 4 u32
constexpr size_t OFF_SELBASE = OFF_SEL2 + 16;                   // 4 u32
constexpr size_t OFF_INV2S   = OFF_SELBASE + 16;                // 4 f32
constexpr size_t OFF_SSUM    = OFF_INV2S + 16;                  // 4*5 f32
constexpr size_t OFF_HIST    = ((OFF_SSUM + 80 + 255) / 256) * 256; // 3 passes * 4 classes * 4096 u32
constexpr size_t WS_END      = OFF_HIST + 3 * NCLS * 4096 * 4;

__device__ __forceinline__ float waveReduceSum(float v) {
#pragma unroll
    for (int o = 32; o > 0; o >>= 1) v += __shfl_down(v, o, 64);
    return v;
}

// round-to-nearest-even f32 -> bf16 (as raw short)
__device__ __forceinline__ short bf16_rne(float x) {
    unsigned u = __float_as_uint(x);
    unsigned r = (u + 0x7FFFu + ((u >> 16) & 1u)) >> 16;
    return (short)r;
}
__device__ __forceinline__ float bf16_to_f32(short h) {
    return __uint_as_float(((unsigned)(unsigned short)h) << 16);
}

// ---------------- row norms of comb ----------------
__global__ __launch_bounds__(256) void k_norms(const float* __restrict__ fs,
                                               const float* __restrict__ ft,
                                               float* __restrict__ norms) {
    int row = blockIdx.x;
    const float* src = row < NSRC ? fs + (size_t)row * DIM : ft + (size_t)(row - NSRC) * DIM;
    float s = 0.f;
    for (int k = threadIdx.x; k < DIM; k += 256) {
        float v = src[k];
        s = fmaf(v, v, s);
    }
    s = waveReduceSum(s);
    __shared__ float ls[4];
    int lane = threadIdx.x & 63, w = threadIdx.x >> 6;
    if (lane == 0) ls[w] = s;
    __syncthreads();
    if (threadIdx.x == 0) norms[row] = ls[0] + ls[1] + ls[2] + ls[3];
}

// ---------------- per-row stats: loss_cls, entropy, w, pseudo, class lists ----------------
__global__ __launch_bounds__(256) void k_rowstats(const float* __restrict__ logits_s,
                                                  const int* __restrict__ labels,
                                                  const float* __restrict__ logits_t,
                                                  float* __restrict__ wbuf,
                                                  int* __restrict__ clsof,
                                                  int* __restrict__ cidx,
                                                  int* __restrict__ ccnt,
                                                  int* __restrict__ cns,
                                                  int* __restrict__ cnt_,
                                                  float* __restrict__ loss2) {
    int tid = blockIdx.x * 256 + threadIdx.x;
    if (tid < NSRC) {
        float4 l = *(const float4*)(logits_s + (size_t)tid * 4);
        float m = fmaxf(fmaxf(l.x, l.y), fmaxf(l.z, l.w));
        float e0 = expf(l.x - m), e1 = expf(l.y - m), e2 = expf(l.z - m), e3 = expf(l.w - m);
        float lse = m + logf(e0 + e1 + e2 + e3);
        int lab = labels[tid];
        float lv = (lab == 0) ? l.x : (lab == 1) ? l.y : (lab == 2) ? l.z : l.w;
        atomicAdd(&loss2[0], lse - lv); // -log p[label]
        clsof[tid] = lab;
        atomicAdd(&cns[lab], 1);
        int pos = atomicAdd(&ccnt[lab], 1);
        cidx[lab * NTOT + pos] = tid;
    } else if (tid < NTOT) {
        int j = tid - NSRC;
        float4 l = *(const float4*)(logits_t + (size_t)j * 4);
        float m = fmaxf(fmaxf(l.x, l.y), fmaxf(l.z, l.w));
        float e0 = expf(l.x - m), e1 = expf(l.y - m), e2 = expf(l.z - m), e3 = expf(l.w - m);
        float s = e0 + e1 + e2 + e3;
        float p0 = e0 / s, p1 = e1 / s, p2 = e2 / s, p3 = e3 / s;
        float ent = 0.f;
        ent -= p0 * logf(p0 + EPSF);
        ent -= p1 * logf(p1 + EPSF);
        ent -= p2 * logf(p2 + EPSF);
        ent -= p3 * logf(p3 + EPSF);
        int bi = 0;
        float bv = l.x;
        if (l.y > bv) { bv = l.y; bi = 1; }
        if (l.z > bv) { bv = l.z; bi = 2; }
        if (l.w > bv) { bv = l.w; bi = 3; }
        float w = 1.f - ent / (logf(4.f) + EPSF);
        wbuf[j] = w;
        clsof[tid] = bi;
        atomicAdd(&loss2[1], ent);
        atomicAdd(&cnt_[bi], 1);
        int pos = atomicAdd(&ccnt[bi], 1);
        cidx[bi * NTOT + pos] = tid;
    }
}

// ---------------- D2 via split-bf16 MFMA Gram ----------------
__global__ __launch_bounds__(256) void k_gemm_d2(const float* __restrict__ fs,
                                                 const float* __restrict__ ft,
                                                 const float* __restrict__ norms,
                                                 float* __restrict__ D2) {
    __shared__ short Ah[64][40], Al[64][40], Bh[64][40], Bl[64][40];
    int t = threadIdx.x;
    int p = blockIdx.x, by = 0;
    while (p >= 32 - by) { p -= 32 - by; ++by; }
    int bx = by + p;
    int rb = by * 64, cb = bx * 64;

    int sr = t >> 2, sc = (t & 3) * 8;
    int arow = rb + sr, brow = cb + sr;
    const float* asrc = (arow < NSRC ? fs + (size_t)arow * DIM : ft + (size_t)(arow - NSRC) * DIM) + sc;
    const float* bsrc = (brow < NSRC ? fs + (size_t)brow * DIM : ft + (size_t)(brow - NSRC) * DIM) + sc;

    int lane = t & 63;
    int q = lane >> 4;
    int lr = lane & 15;
    int wid = t >> 6;
    int wr = wid >> 1, wc = wid & 1;

    f32x4 acc[2][2] = {};

    for (int k0 = 0; k0 < DIM; k0 += 32) {
        __syncthreads();
        {
            float4 v0 = *(const float4*)(asrc + k0);
            float4 v1 = *(const float4*)(asrc + k0 + 4);
            short8v h, l;
            float vv[8] = {v0.x, v0.y, v0.z, v0.w, v1.x, v1.y, v1.z, v1.w};
#pragma unroll
            for (int i = 0; i < 8; ++i) {
                short hb = bf16_rne(vv[i]);
                h[i] = hb;
                l[i] = bf16_rne(vv[i] - bf16_to_f32(hb));
            }
            *(short8v*)&Ah[sr][sc] = h;
            *(short8v*)&Al[sr][sc] = l;
            v0 = *(const float4*)(bsrc + k0);
            v1 = *(const float4*)(bsrc + k0 + 4);
            float uu[8] = {v0.x, v0.y, v0.z, v0.w, v1.x, v1.y, v1.z, v1.w};
#pragma unroll
            for (int i = 0; i < 8; ++i) {
                short hb = bf16_rne(uu[i]);
                h[i] = hb;
                l[i] = bf16_rne(uu[i] - bf16_to_f32(hb));
            }
            *(short8v*)&Bh[sr][sc] = h;
            *(short8v*)&Bl[sr][sc] = l;
        }
        __syncthreads();
        short8v ah[2], al[2], bh[2], bl[2];
#pragma unroll
        for (int mi = 0; mi < 2; ++mi) {
            int r = wr * 32 + mi * 16 + lr;
            ah[mi] = *(short8v*)&Ah[r][q * 8];
            al[mi] = *(short8v*)&Al[r][q * 8];
        }
#pragma unroll
        for (int ni = 0; ni < 2; ++ni) {
            int r = wc * 32 + ni * 16 + lr;
            bh[ni] = *(short8v*)&Bh[r][q * 8];
            bl[ni] = *(short8v*)&Bl[r][q * 8];
        }
#pragma unroll
        for (int mi = 0; mi < 2; ++mi)
#pragma unroll
            for (int ni = 0; ni < 2; ++ni) {
                acc[mi][ni] = __builtin_amdgcn_mfma_f32_16x16x32_bf16(ah[mi], bh[ni], acc[mi][ni], 0, 0, 0);
                acc[mi][ni] = __builtin_amdgcn_mfma_f32_16x16x32_bf16(ah[mi], bl[ni], acc[mi][ni], 0, 0, 0);
                acc[mi][ni] = __builtin_amdgcn_mfma_f32_16x16x32_bf16(al[mi], bh[ni], acc[mi][ni], 0, 0, 0);
            }
    }

    bool offdiag = (bx != by);
#pragma unroll
    for (int mi = 0; mi < 2; ++mi)
#pragma unroll
        for (int ni = 0; ni < 2; ++ni)
#pragma unroll
            for (int i = 0; i < 4; ++i) {
                int gi = rb + wr * 32 + mi * 16 + q * 4 + i;
                int gj = cb + wc * 32 + ni * 16 + lr;
                float d = fmaxf(norms[gi] + norms[gj] - 2.f * acc[mi][ni][i], 0.f);
                D2[(size_t)gi * NTOT + gj] = d;
                if (offdiag) D2[(size_t)gj * NTOT + gi] = d;
            }
}

// ---------------- 12/12/8 radix pass over class pairs (i<j global, both in class) --
// Coalesced row sweep: per class row i, lanes sweep cols j>i, filter clsof[j]==c
// (clsof cached in LDS). Histogram accumulated in LDS (4096 u32 = 16 KB), merged
// to global with atomics only on nonzero bins -> no same-address storm.
// pass 1: key = bits>>20 (few distinct bins -> ballot-aggregated LDS adds)
// pass 2: key = (bits>>8)&0xFFF, filtered by sel1  (spread -> direct LDS atomics)
// pass 3: key = bits&0xFF, filtered by sel1,sel2   (spread -> direct LDS atomics)
__global__ __launch_bounds__(256) void k_radixpass(const float* __restrict__ D2,
                                                   const int* __restrict__ cidx,
                                                   const int* __restrict__ ccnt,
                                                   const int* __restrict__ clsof,
                                                   unsigned* __restrict__ hist,
                                                   const unsigned* __restrict__ sel1,
                                                   const unsigned* __restrict__ sel2,
                                                   int pass) {
    int c = blockIdx.y;
    int n = ccnt[c];
    if (n < 2) return;
    const int* idx = cidx + c * NTOT;
    unsigned* gh = hist + ((size_t)(pass - 1) * NCLS + c) * 4096;
    __shared__ unsigned lh[4096];
    __shared__ unsigned char lcls[NTOT];
    for (int b = threadIdx.x; b < 4096; b += 256) lh[b] = 0;
    for (int j = threadIdx.x; j < NTOT; j += 256) lcls[j] = (unsigned char)clsof[j];
    __syncthreads();
    unsigned s1 = (pass >= 2) ? sel1[c] : 0u;
    unsigned s2 = (pass >= 3) ? sel2[c] : 0u;
    int lane = threadIdx.x & 63;

    for (int a = blockIdx.x; a < n; a += gridDim.x) {
        int i = idx[a];
        const float* drow = D2 + (size_t)i * NTOT;
        for (int j = i + 1 + threadIdx.x; j < NTOT; j += 256) {
            bool want = (lcls[j] == (unsigned char)c);
            unsigned bin = 0;
            if (want) {
                unsigned bits = __float_as_uint(drow[j]);
                if (pass == 1) {
                    bin = bits >> 20;
                } else if (pass == 2) {
                    want = (bits >> 20) == s1;
                    bin = (bits >> 8) & 0xFFFu;
                } else {
                    want = ((bits >> 20) == s1) && (((bits >> 8) & 0xFFFu) == s2);
                    bin = bits & 0xFFu;
                }
            }
            if (pass == 1) {
                // ballot-aggregate: pass-1 keys cluster into 1-3 bins
                while (__any(want)) {
                    unsigned long long m = __ballot(want);
                    int leader = __ffsll((long long)m) - 1;
                    unsigned lbin = __shfl(bin, leader, 64);
                    bool same = want && (bin == lbin);
                    unsigned long long sm = __ballot(same);
                    if (lane == leader) atomicAdd(&lh[lbin], (unsigned)__popcll(sm));
                    want = want && !same;
                }
            } else {
                if (want) atomicAdd(&lh[bin], 1u);
            }
        }
    }
    __syncthreads();
    for (int b = threadIdx.x; b < 4096; b += 256) {
        unsigned v = lh[b];
        if (v) atomicAdd(gh + b, v);
    }
}

// ---------------- select k-th within a 4096-bin histogram level ----------------
__global__ __launch_bounds__(256) void k_select(const unsigned* __restrict__ hist,
                                                const int* __restrict__ ccnt,
                                                unsigned* __restrict__ sel1,
                                                unsigned* __restrict__ sel2,
                                                unsigned* __restrict__ selbase,
                                                float* __restrict__ inv2s,
                                                int pass) {
    int c = blockIdx.x;
    int t = threadIdx.x;
    long long n = ccnt[c];
    long long P = n * (n - 1) / 2;
    if (P == 0) {
        if (t == 0 && pass == 3) {
            inv2s[c] = 1.f / (2.f * (1.0f + 1e-6f) + EPSF);
        }
        return;
    }
    unsigned target = (unsigned)((P - 1) / 2) + 1u - selbase[c];
    const unsigned* h = hist + ((size_t)(pass - 1) * NCLS + c) * 4096;

    unsigned local = 0;
    int b0 = t * 16;
    for (int b = b0; b < b0 + 16; ++b) local += h[b];
    __shared__ unsigned ls[256];
    __shared__ unsigned sbin;
    ls[t] = local;
    if (t == 0) sbin = 0xFFFFFFFFu;
    __syncthreads();
    unsigned prefix = 0;
    for (int i = 0; i < t; ++i) prefix += ls[i];

    unsigned cum = prefix;
    unsigned fbin = 0xFFFFFFFFu, fbase = 0;
    for (int b = b0; b < b0 + 16; ++b) {
        unsigned hv = h[b];
        if (cum + hv >= target) { fbin = (unsigned)b; fbase = cum; break; }
        cum += hv;
    }
    if (fbin != 0xFFFFFFFFu) atomicMin(&sbin, fbin);
    __syncthreads();
    if (fbin == sbin && fbin != 0xFFFFFFFFu) {
        if (pass == 1) {
            sel1[c] = fbin;
            selbase[c] += fbase;
        } else if (pass == 2) {
            sel2[c] = fbin;
            selbase[c] += fbase;
        } else {
            unsigned bits = (sel1[c] << 20) | (sel2[c] << 8) | fbin;
            float med = __uint_as_float(bits);
            inv2s[c] = 1.f / (2.f * (med + 1e-6f) + EPSF);
        }
    }
}

// ---------------- masked kernel-matrix sums per class (gather over class lists) --
__global__ __launch_bounds__(256) void k_sums(const float* __restrict__ D2,
                                              const int* __restrict__ cidx,
                                              const int* __restrict__ ccnt,
                                              const float* __restrict__ wbuf,
                                              const float* __restrict__ inv2s,
                                              float* __restrict__ S) {
    int c = blockIdx.y;
    int n = ccnt[c];
    if (n == 0) return;
    const int* idx = cidx + c * NTOT;
    float is2 = inv2s[c];
    float ss = 0.f, tt = 0.f, st = 0.f, trs = 0.f, trt = 0.f;
    for (int a = blockIdx.x; a < n; a += gridDim.x) {
        int i = idx[a];
        bool si = i < NSRC;
        float wi = si ? 1.f : wbuf[i - NSRC];
        const float* drow = D2 + (size_t)i * NTOT;
        for (int b = threadIdx.x; b < n; b += 256) {
            int j = idx[b];
            float d = drow[j];
            float Kv = expf(-d * is2);
            float K2 = Kv * Kv;
            bool sj = j < NSRC;
            if (si && sj) {
                ss += K2;
            } else if (!si && !sj) {
                float ww = wi * wbuf[j - NSRC];
                tt += ww * ww * K2;
            } else {
                st += K2;
            }
            if (i == j) {
                if (si) trs += Kv;
                else trt += wi * wi * Kv;
            }
        }
    }
    ss = waveReduceSum(ss);
    tt = waveReduceSum(tt);
    st = waveReduceSum(st);
    trs = waveReduceSum(trs);
    trt = waveReduceSum(trt);
    __shared__ float red[4][5];
    int lane = threadIdx.x & 63, w = threadIdx.x >> 6;
    if (lane == 0) { red[w][0] = ss; red[w][1] = tt; red[w][2] = st; red[w][3] = trs; red[w][4] = trt; }
    __syncthreads();
    if (threadIdx.x < 5) {
        float v = red[0][threadIdx.x] + red[1][threadIdx.x] + red[2][threadIdx.x] + red[3][threadIdx.x];
        atomicAdd(&S[c * 5 + threadIdx.x], v);
    }
}

// ---------------- final combine ----------------
__global__ void k_final(const float* __restrict__ S,
                        const int* __restrict__ cns,
                        const int* __restrict__ cnt_,
                        const float* __restrict__ loss2,
                        float* __restrict__ out) {
    if (threadIdx.x != 0 || blockIdx.x != 0) return;
    float csum = 0.f;
    int nv = 0;
    for (int c = 0; c < NCLS; ++c) {
        float Sss = S[c * 5 + 0], Stt = S[c * 5 + 1], Sst2 = S[c * 5 + 2];
        float Tss = S[c * 5 + 3], Ttt = S[c * 5 + 4];
        float trs = Tss + EPSF, trt = Ttt + EPSF, trm = Tss + Ttt + EPSF;
        float h2s = -log2f(Sss / (trs * trs) + EPSF);
        float h2t = -log2f(Stt / (trt * trt) + EPSF);
        float h2m = -log2f((Sss + Stt + Sst2) / (trm * trm) + EPSF);
        if (cns[c] >= 2 && cnt_[c] >= 2) {
            csum += h2m - 0.5f * (h2s + h2t);
            nv++;
        }
    }
    float creda = (nv > 0) ? csum / (float)nv : 0.f;
    out[0] = loss2[0] * (1.f / 1024.f) + creda + 0.1f * (loss2[1] * (1.f / 1024.f));
}

extern "C" void kernel_launch(void* const* d_in, const int* in_sizes, int n_in,
                              void* d_out, int out_size, void* d_ws, size_t ws_size,
                              hipStream_t stream) {
    const float* fs  = (const float*)d_in[0];
    const float* ls  = (const float*)d_in[1];
    const int*   lab = (const int*)d_in[2];
    const float* ft  = (const float*)d_in[3];
    const float* lt  = (const float*)d_in[4];
    float* out = (float*)d_out;
    char* ws = (char*)d_ws;

    float*    D2      = (float*)(ws + OFF_D2);
    float*    wbuf    = (float*)(ws + OFF_WBUF);
    float*    norms   = (float*)(ws + OFF_NORMS);
    int*      clsof   = (int*)(ws + OFF_CLSOF);
    int*      cidx    = (int*)(ws + OFF_CIDX);
    int*      ccnt    = (int*)(ws + OFF_CCNT);
    int*      cns     = (int*)(ws + OFF_CNS);
    int*      cnt_    = (int*)(ws + OFF_CNT);
    float*    loss2   = (float*)(ws + OFF_LOSS2);
    unsigned* sel1    = (unsigned*)(ws + OFF_SEL1);
    unsigned* sel2    = (unsigned*)(ws + OFF_SEL2);
    unsigned* selbase = (unsigned*)(ws + OFF_SELBASE);
    float*    inv2s   = (float*)(ws + OFF_INV2S);
    float*    Ssum    = (float*)(ws + OFF_SSUM);
    unsigned* hist    = (unsigned*)(ws + OFF_HIST);

    // zero the counters/accumulators/histograms (ws is poisoned 0xAA each call)
    hipMemsetAsync(ws + OFF_CCNT, 0, WS_END - OFF_CCNT, stream);

    k_norms<<<NTOT, 256, 0, stream>>>(fs, ft, norms);
    k_rowstats<<<NTOT / 256, 256, 0, stream>>>(ls, lab, lt, wbuf, clsof, cidx, ccnt, cns, cnt_, loss2);
    k_gemm_d2<<<528, 256, 0, stream>>>(fs, ft, norms, D2);
    k_radixpass<<<dim3(64, NCLS), 256, 0, stream>>>(D2, cidx, ccnt, clsof, hist, sel1, sel2, 1);
    k_select<<<NCLS, 256, 0, stream>>>(hist, ccnt, sel1, sel2, selbase, inv2s, 1);
    k_radixpass<<<dim3(64, NCLS), 256, 0, stream>>>(D2, cidx, ccnt, clsof, hist, sel1, sel2, 2);
    k_select<<<NCLS, 256, 0, stream>>>(hist, ccnt, sel1, sel2, selbase, inv2s, 2);
    k_radixpass<<<dim3(64, NCLS), 256, 0, stream>>>(D2, cidx, ccnt, clsof, hist, sel1, sel2, 3);
    k_select<<<NCLS, 256, 0, stream>>>(hist, ccnt, sel1, sel2, selbase, inv2s, 3);
    k_sums<<<dim3(64, NCLS), 256, 0, stream>>>(D2, cidx, ccnt, wbuf, inv2s, Ssum);
    k_final<<<1, 64, 0, stream>>>(Ssum, cns, cnt_, loss2, out);
}

// Round 15
// 264.311 us; speedup vs baseline: 4.3561x; 1.0702x over previous
//
#include <hip/hip_runtime.h>
#include <math.h>

#define EPSF 1e-8f
#define NSRC 1024
#define NTGT 1024
#define NTOT 2048
#define DIM  2048
#define NCLS 4

typedef __attribute__((ext_vector_type(8))) short short8v;
typedef __attribute__((ext_vector_type(4))) float f32x4;

// ---------------- workspace layout (bytes) ----------------
constexpr size_t OFF_D2      = 0;                               // 2048*2048 f32
constexpr size_t OFF_WBUF    = (size_t)NTOT * NTOT * 4;         // 1024 f32
constexpr size_t OFF_NORMS   = OFF_WBUF + 1024 * 4;             // 2048 f32
constexpr size_t OFF_CLSOF   = OFF_NORMS + 2048 * 4;            // 2048 i32
constexpr size_t OFF_CIDX    = OFF_CLSOF + 2048 * 4;            // 4*2048 i32
constexpr size_t OFF_CCNT    = OFF_CIDX + 4 * 2048 * 4;         // 4 i32  <-- zero region starts here
constexpr size_t OFF_CNS     = OFF_CCNT + 16;                   // 4 i32
constexpr size_t OFF_CNT     = OFF_CNS + 16;                    // 4 i32
constexpr size_t OFF_LOSS2   = OFF_CNT + 16;                    // 2 f32
constexpr size_t OFF_SEL1    = OFF_LOSS2 + 16;                  // 4 u32
constexpr size_t OFF_SEL2    = OFF_SEL1 + 16;                   // 4 u32
constexpr size_t OFF_SELBASE = OFF_SEL2 + 16;                   // 4 u32
constexpr size_t OFF_INV2S   = OFF_SELBASE + 16;                // 4 f32
constexpr size_t OFF_SSUM    = OFF_INV2S + 16;                  // 4*5 f32
constexpr size_t OFF_HIST    = ((OFF_SSUM + 80 + 255) / 256) * 256; // 3 passes * 4 classes * 4096 u32
constexpr size_t WS_END      = OFF_HIST + 3 * NCLS * 4096 * 4;
// optional pre-split bf16 buffers (used only if ws_size permits)
constexpr size_t OFF_FH      = ((WS_END + 255) / 256) * 256;    // NTOT*DIM bf16 (hi)
constexpr size_t OFF_FL      = OFF_FH + (size_t)NTOT * DIM * 2; // NTOT*DIM bf16 (lo)
constexpr size_t WS_END_PRE  = OFF_FL + (size_t)NTOT * DIM * 2;

__device__ __forceinline__ float waveReduceSum(float v) {
#pragma unroll
    for (int o = 32; o > 0; o >>= 1) v += __shfl_down(v, o, 64);
    return v;
}

// round-to-nearest-even f32 -> bf16 (as raw short)
__device__ __forceinline__ short bf16_rne(float x) {
    unsigned u = __float_as_uint(x);
    unsigned r = (u + 0x7FFFu + ((u >> 16) & 1u)) >> 16;
    return (short)r;
}
__device__ __forceinline__ float bf16_to_f32(short h) {
    return __uint_as_float(((unsigned)(unsigned short)h) << 16);
}

// ---------------- row norms of comb (fallback path) ----------------
__global__ __launch_bounds__(256) void k_norms(const float* __restrict__ fs,
                                               const float* __restrict__ ft,
                                               float* __restrict__ norms) {
    int row = blockIdx.x;
    const float* src = row < NSRC ? fs + (size_t)row * DIM : ft + (size_t)(row - NSRC) * DIM;
    float s = 0.f;
    for (int k = threadIdx.x; k < DIM; k += 256) {
        float v = src[k];
        s = fmaf(v, v, s);
    }
    s = waveReduceSum(s);
    __shared__ float ls[4];
    int lane = threadIdx.x & 63, w = threadIdx.x >> 6;
    if (lane == 0) ls[w] = s;
    __syncthreads();
    if (threadIdx.x == 0) norms[row] = ls[0] + ls[1] + ls[2] + ls[3];
}

// ---------------- one-time hi/lo bf16 split + norms (pre path) ----------------
__global__ __launch_bounds__(256) void k_split(const float* __restrict__ fs,
                                               const float* __restrict__ ft,
                                               short* __restrict__ Fh,
                                               short* __restrict__ Fl,
                                               float* __restrict__ norms) {
    int row = blockIdx.x;
    const float* src = row < NSRC ? fs + (size_t)row * DIM : ft + (size_t)(row - NSRC) * DIM;
    int t = threadIdx.x;
    float4 v0 = *(const float4*)(src + t * 8);
    float4 v1 = *(const float4*)(src + t * 8 + 4);
    float vv[8] = {v0.x, v0.y, v0.z, v0.w, v1.x, v1.y, v1.z, v1.w};
    short8v h, l;
    float s = 0.f;
#pragma unroll
    for (int i = 0; i < 8; ++i) {
        s = fmaf(vv[i], vv[i], s);
        short hb = bf16_rne(vv[i]);
        h[i] = hb;
        l[i] = bf16_rne(vv[i] - bf16_to_f32(hb));
    }
    *(short8v*)&Fh[(size_t)row * DIM + t * 8] = h;
    *(short8v*)&Fl[(size_t)row * DIM + t * 8] = l;
    s = waveReduceSum(s);
    __shared__ float ls[4];
    int lane = t & 63, w = t >> 6;
    if (lane == 0) ls[w] = s;
    __syncthreads();
    if (t == 0) norms[row] = ls[0] + ls[1] + ls[2] + ls[3];
}

// ---------------- per-row stats ----------------
__global__ __launch_bounds__(256) void k_rowstats(const float* __restrict__ logits_s,
                                                  const int* __restrict__ labels,
                                                  const float* __restrict__ logits_t,
                                                  float* __restrict__ wbuf,
                                                  int* __restrict__ clsof,
                                                  int* __restrict__ cidx,
                                                  int* __restrict__ ccnt,
                                                  int* __restrict__ cns,
                                                  int* __restrict__ cnt_,
                                                  float* __restrict__ loss2) {
    int tid = blockIdx.x * 256 + threadIdx.x;
    if (tid < NSRC) {
        float4 l = *(const float4*)(logits_s + (size_t)tid * 4);
        float m = fmaxf(fmaxf(l.x, l.y), fmaxf(l.z, l.w));
        float e0 = expf(l.x - m), e1 = expf(l.y - m), e2 = expf(l.z - m), e3 = expf(l.w - m);
        float lse = m + logf(e0 + e1 + e2 + e3);
        int lab = labels[tid];
        float lv = (lab == 0) ? l.x : (lab == 1) ? l.y : (lab == 2) ? l.z : l.w;
        atomicAdd(&loss2[0], lse - lv);
        clsof[tid] = lab;
        atomicAdd(&cns[lab], 1);
        int pos = atomicAdd(&ccnt[lab], 1);
        cidx[lab * NTOT + pos] = tid;
    } else if (tid < NTOT) {
        int j = tid - NSRC;
        float4 l = *(const float4*)(logits_t + (size_t)j * 4);
        float m = fmaxf(fmaxf(l.x, l.y), fmaxf(l.z, l.w));
        float e0 = expf(l.x - m), e1 = expf(l.y - m), e2 = expf(l.z - m), e3 = expf(l.w - m);
        float s = e0 + e1 + e2 + e3;
        float p0 = e0 / s, p1 = e1 / s, p2 = e2 / s, p3 = e3 / s;
        float ent = 0.f;
        ent -= p0 * logf(p0 + EPSF);
        ent -= p1 * logf(p1 + EPSF);
        ent -= p2 * logf(p2 + EPSF);
        ent -= p3 * logf(p3 + EPSF);
        int bi = 0;
        float bv = l.x;
        if (l.y > bv) { bv = l.y; bi = 1; }
        if (l.z > bv) { bv = l.z; bi = 2; }
        if (l.w > bv) { bv = l.w; bi = 3; }
        float w = 1.f - ent / (logf(4.f) + EPSF);
        wbuf[j] = w;
        clsof[tid] = bi;
        atomicAdd(&loss2[1], ent);
        atomicAdd(&cnt_[bi], 1);
        int pos = atomicAdd(&ccnt[bi], 1);
        cidx[bi * NTOT + pos] = tid;
    }
}

// ---------------- D2 GEMM, pre-split bf16 path ----------------
// BK=64, linear LDS [64][64] bf16 with XOR chunk swizzle (16B granules):
// value (row, chunk) stored at chunk^(row&7). Writes spread evenly over banks
// (8-round minimum for b128, no excess); frag reads hit 8 distinct chunks per
// 16-lane group -> all 32 banks, 2-way (free). Same swizzle on A and B sides.
__global__ __launch_bounds__(256) void k_gemm_pre(const short* __restrict__ Fh,
                                                  const short* __restrict__ Fl,
                                                  const float* __restrict__ norms,
                                                  float* __restrict__ D2) {
    __shared__ short LAh[64 * 64], LAl[64 * 64], LBh[64 * 64], LBl[64 * 64]; // 32 KB
    int t = threadIdx.x;
    int p = blockIdx.x, by = 0;
    while (p >= 32 - by) { p -= 32 - by; ++by; }
    int bx = by + p;
    int rb = by * 64, cb = bx * 64;

    // staging: thread t -> row sr, logical chunks c0, c0+1 (chunk = 8 bf16 = 16B)
    int sr = t >> 2;
    int c0 = (t & 3) * 2;
    const short* gAh = Fh + (size_t)(rb + sr) * DIM;
    const short* gAl = Fl + (size_t)(rb + sr) * DIM;
    const short* gBh = Fh + (size_t)(cb + sr) * DIM;
    const short* gBl = Fl + (size_t)(cb + sr) * DIM;
    int st0 = sr * 64 + ((c0 ^ (sr & 7)) * 8);
    int st1 = sr * 64 + (((c0 + 1) ^ (sr & 7)) * 8);
    int go0 = c0 * 8, go1 = (c0 + 1) * 8;

    int lane = t & 63;
    int q = lane >> 4, lr = lane & 15;
    int wid = t >> 6, wr = wid >> 1, wc = wid & 1;

    f32x4 acc[2][2] = {};

    for (int k0 = 0; k0 < DIM; k0 += 64) {
        __syncthreads();
        *(short8v*)&LAh[st0] = *(const short8v*)(gAh + k0 + go0);
        *(short8v*)&LAh[st1] = *(const short8v*)(gAh + k0 + go1);
        *(short8v*)&LAl[st0] = *(const short8v*)(gAl + k0 + go0);
        *(short8v*)&LAl[st1] = *(const short8v*)(gAl + k0 + go1);
        *(short8v*)&LBh[st0] = *(const short8v*)(gBh + k0 + go0);
        *(short8v*)&LBh[st1] = *(const short8v*)(gBh + k0 + go1);
        *(short8v*)&LBl[st0] = *(const short8v*)(gBl + k0 + go0);
        *(short8v*)&LBl[st1] = *(const short8v*)(gBl + k0 + go1);
        __syncthreads();
#pragma unroll
        for (int ks = 0; ks < 2; ++ks) {
            short8v ah[2], al[2], bh[2], bl[2];
#pragma unroll
            for (int mi = 0; mi < 2; ++mi) {
                int r = wr * 32 + mi * 16 + lr;
                int ch = ((ks * 4 + q) ^ (r & 7)) * 8;
                ah[mi] = *(short8v*)&LAh[r * 64 + ch];
                al[mi] = *(short8v*)&LAl[r * 64 + ch];
            }
#pragma unroll
            for (int ni = 0; ni < 2; ++ni) {
                int r = wc * 32 + ni * 16 + lr;
                int ch = ((ks * 4 + q) ^ (r & 7)) * 8;
                bh[ni] = *(short8v*)&LBh[r * 64 + ch];
                bl[ni] = *(short8v*)&LBl[r * 64 + ch];
            }
#pragma unroll
            for (int mi = 0; mi < 2; ++mi)
#pragma unroll
                for (int ni = 0; ni < 2; ++ni) {
                    acc[mi][ni] = __builtin_amdgcn_mfma_f32_16x16x32_bf16(ah[mi], bh[ni], acc[mi][ni], 0, 0, 0);
                    acc[mi][ni] = __builtin_amdgcn_mfma_f32_16x16x32_bf16(ah[mi], bl[ni], acc[mi][ni], 0, 0, 0);
                    acc[mi][ni] = __builtin_amdgcn_mfma_f32_16x16x32_bf16(al[mi], bh[ni], acc[mi][ni], 0, 0, 0);
                }
        }
    }

    bool offdiag = (bx != by);
#pragma unroll
    for (int mi = 0; mi < 2; ++mi)
#pragma unroll
        for (int ni = 0; ni < 2; ++ni)
#pragma unroll
            for (int i = 0; i < 4; ++i) {
                int gi = rb + wr * 32 + mi * 16 + q * 4 + i;
                int gj = cb + wc * 32 + ni * 16 + lr;
                float d = fmaxf(norms[gi] + norms[gj] - 2.f * acc[mi][ni][i], 0.f);
                D2[(size_t)gi * NTOT + gj] = d;
                if (offdiag) D2[(size_t)gj * NTOT + gi] = d;
            }
}

// ---------------- D2 GEMM, f32-convert fallback (measured-good) ----------------
__global__ __launch_bounds__(256) void k_gemm_d2(const float* __restrict__ fs,
                                                 const float* __restrict__ ft,
                                                 const float* __restrict__ norms,
                                                 float* __restrict__ D2) {
    __shared__ short Ah[64][40], Al[64][40], Bh[64][40], Bl[64][40];
    int t = threadIdx.x;
    int p = blockIdx.x, by = 0;
    while (p >= 32 - by) { p -= 32 - by; ++by; }
    int bx = by + p;
    int rb = by * 64, cb = bx * 64;

    int sr = t >> 2, sc = (t & 3) * 8;
    int arow = rb + sr, brow = cb + sr;
    const float* asrc = (arow < NSRC ? fs + (size_t)arow * DIM : ft + (size_t)(arow - NSRC) * DIM) + sc;
    const float* bsrc = (brow < NSRC ? fs + (size_t)brow * DIM : ft + (size_t)(brow - NSRC) * DIM) + sc;

    int lane = t & 63;
    int q = lane >> 4;
    int lr = lane & 15;
    int wid = t >> 6;
    int wr = wid >> 1, wc = wid & 1;

    f32x4 acc[2][2] = {};

    for (int k0 = 0; k0 < DIM; k0 += 32) {
        __syncthreads();
        {
            float4 v0 = *(const float4*)(asrc + k0);
            float4 v1 = *(const float4*)(asrc + k0 + 4);
            short8v h, l;
            float vv[8] = {v0.x, v0.y, v0.z, v0.w, v1.x, v1.y, v1.z, v1.w};
#pragma unroll
            for (int i = 0; i < 8; ++i) {
                short hb = bf16_rne(vv[i]);
                h[i] = hb;
                l[i] = bf16_rne(vv[i] - bf16_to_f32(hb));
            }
            *(short8v*)&Ah[sr][sc] = h;
            *(short8v*)&Al[sr][sc] = l;
            v0 = *(const float4*)(bsrc + k0);
            v1 = *(const float4*)(bsrc + k0 + 4);
            float uu[8] = {v0.x, v0.y, v0.z, v0.w, v1.x, v1.y, v1.z, v1.w};
#pragma unroll
            for (int i = 0; i < 8; ++i) {
                short hb = bf16_rne(uu[i]);
                h[i] = hb;
                l[i] = bf16_rne(uu[i] - bf16_to_f32(hb));
            }
            *(short8v*)&Bh[sr][sc] = h;
            *(short8v*)&Bl[sr][sc] = l;
        }
        __syncthreads();
        short8v ah[2], al[2], bh[2], bl[2];
#pragma unroll
        for (int mi = 0; mi < 2; ++mi) {
            int r = wr * 32 + mi * 16 + lr;
            ah[mi] = *(short8v*)&Ah[r][q * 8];
            al[mi] = *(short8v*)&Al[r][q * 8];
        }
#pragma unroll
        for (int ni = 0; ni < 2; ++ni) {
            int r = wc * 32 + ni * 16 + lr;
            bh[ni] = *(short8v*)&Bh[r][q * 8];
            bl[ni] = *(short8v*)&Bl[r][q * 8];
        }
#pragma unroll
        for (int mi = 0; mi < 2; ++mi)
#pragma unroll
            for (int ni = 0; ni < 2; ++ni) {
                acc[mi][ni] = __builtin_amdgcn_mfma_f32_16x16x32_bf16(ah[mi], bh[ni], acc[mi][ni], 0, 0, 0);
                acc[mi][ni] = __builtin_amdgcn_mfma_f32_16x16x32_bf16(ah[mi], bl[ni], acc[mi][ni], 0, 0, 0);
                acc[mi][ni] = __builtin_amdgcn_mfma_f32_16x16x32_bf16(al[mi], bh[ni], acc[mi][ni], 0, 0, 0);
            }
    }

    bool offdiag = (bx != by);
#pragma unroll
    for (int mi = 0; mi < 2; ++mi)
#pragma unroll
        for (int ni = 0; ni < 2; ++ni)
#pragma unroll
            for (int i = 0; i < 4; ++i) {
                int gi = rb + wr * 32 + mi * 16 + q * 4 + i;
                int gj = cb + wc * 32 + ni * 16 + lr;
                float d = fmaxf(norms[gi] + norms[gj] - 2.f * acc[mi][ni][i], 0.f);
                D2[(size_t)gi * NTOT + gj] = d;
                if (offdiag) D2[(size_t)gj * NTOT + gi] = d;
            }
}

// ---------------- 12/12/8 radix pass over class pairs ----------------
__global__ __launch_bounds__(256) void k_radixpass(const float* __restrict__ D2,
                                                   const int* __restrict__ cidx,
                                                   const int* __restrict__ ccnt,
                                                   const int* __restrict__ clsof,
                                                   unsigned* __restrict__ hist,
                                                   const unsigned* __restrict__ sel1,
                                                   const unsigned* __restrict__ sel2,
                                                   int pass) {
    int c = blockIdx.y;
    int n = ccnt[c];
    if (n < 2) return;
    const int* idx = cidx + c * NTOT;
    unsigned* gh = hist + ((size_t)(pass - 1) * NCLS + c) * 4096;
    __shared__ unsigned lh[4096];
    __shared__ unsigned char lcls[NTOT];
    for (int b = threadIdx.x; b < 4096; b += 256) lh[b] = 0;
    for (int j = threadIdx.x; j < NTOT; j += 256) lcls[j] = (unsigned char)clsof[j];
    __syncthreads();
    unsigned s1 = (pass >= 2) ? sel1[c] : 0u;
    unsigned s2 = (pass >= 3) ? sel2[c] : 0u;
    int lane = threadIdx.x & 63;

    for (int a = blockIdx.x; a < n; a += gridDim.x) {
        int i = idx[a];
        const float* drow = D2 + (size_t)i * NTOT;
        for (int j = i + 1 + threadIdx.x; j < NTOT; j += 256) {
            bool want = (lcls[j] == (unsigned char)c);
            unsigned bin = 0;
            if (want) {
                unsigned bits = __float_as_uint(drow[j]);
                if (pass == 1) {
                    bin = bits >> 20;
                } else if (pass == 2) {
                    want = (bits >> 20) == s1;
                    bin = (bits >> 8) & 0xFFFu;
                } else {
                    want = ((bits >> 20) == s1) && (((bits >> 8) & 0xFFFu) == s2);
                    bin = bits & 0xFFu;
                }
            }
            if (pass == 1) {
                while (__any(want)) {
                    unsigned long long m = __ballot(want);
                    int leader = __ffsll((long long)m) - 1;
                    unsigned lbin = __shfl(bin, leader, 64);
                    bool same = want && (bin == lbin);
                    unsigned long long sm = __ballot(same);
                    if (lane == leader) atomicAdd(&lh[lbin], (unsigned)__popcll(sm));
                    want = want && !same;
                }
            } else {
                if (want) atomicAdd(&lh[bin], 1u);
            }
        }
    }
    __syncthreads();
    for (int b = threadIdx.x; b < 4096; b += 256) {
        unsigned v = lh[b];
        if (v) atomicAdd(gh + b, v);
    }
}

// ---------------- select k-th within a 4096-bin histogram level ----------------
__global__ __launch_bounds__(256) void k_select(const unsigned* __restrict__ hist,
                                                const int* __restrict__ ccnt,
                                                unsigned* __restrict__ sel1,
                                                unsigned* __restrict__ sel2,
                                                unsigned* __restrict__ selbase,
                                                float* __restrict__ inv2s,
                                                int pass) {
    int c = blockIdx.x;
    int t = threadIdx.x;
    long long n = ccnt[c];
    long long P = n * (n - 1) / 2;
    if (P == 0) {
        if (t == 0 && pass == 3) {
            inv2s[c] = 1.f / (2.f * (1.0f + 1e-6f) + EPSF);
        }
        return;
    }
    unsigned target = (unsigned)((P - 1) / 2) + 1u - selbase[c];
    const unsigned* h = hist + ((size_t)(pass - 1) * NCLS + c) * 4096;

    unsigned local = 0;
    int b0 = t * 16;
    for (int b = b0; b < b0 + 16; ++b) local += h[b];
    __shared__ unsigned ls[256];
    __shared__ unsigned sbin;
    ls[t] = local;
    if (t == 0) sbin = 0xFFFFFFFFu;
    __syncthreads();
    unsigned prefix = 0;
    for (int i = 0; i < t; ++i) prefix += ls[i];

    unsigned cum = prefix;
    unsigned fbin = 0xFFFFFFFFu, fbase = 0;
    for (int b = b0; b < b0 + 16; ++b) {
        unsigned hv = h[b];
        if (cum + hv >= target) { fbin = (unsigned)b; fbase = cum; break; }
        cum += hv;
    }
    if (fbin != 0xFFFFFFFFu) atomicMin(&sbin, fbin);
    __syncthreads();
    if (fbin == sbin && fbin != 0xFFFFFFFFu) {
        if (pass == 1) {
            sel1[c] = fbin;
            selbase[c] += fbase;
        } else if (pass == 2) {
            sel2[c] = fbin;
            selbase[c] += fbase;
        } else {
            unsigned bits = (sel1[c] << 20) | (sel2[c] << 8) | fbin;
            float med = __uint_as_float(bits);
            inv2s[c] = 1.f / (2.f * (med + 1e-6f) + EPSF);
        }
    }
}

// ---------------- masked kernel-matrix sums per class ----------------
__global__ __launch_bounds__(256) void k_sums(const float* __restrict__ D2,
                                              const int* __restrict__ cidx,
                                              const int* __restrict__ ccnt,
                                              const float* __restrict__ wbuf,
                                              const float* __restrict__ inv2s,
                                              float* __restrict__ S) {
    int c = blockIdx.y;
    int n = ccnt[c];
    if (n == 0) return;
    const int* idx = cidx + c * NTOT;
    float is2 = inv2s[c];
    float ss = 0.f, tt = 0.f, st = 0.f, trs = 0.f, trt = 0.f;
    for (int a = blockIdx.x; a < n; a += gridDim.x) {
        int i = idx[a];
        bool si = i < NSRC;
        float wi = si ? 1.f : wbuf[i - NSRC];
        const float* drow = D2 + (size_t)i * NTOT;
        for (int b = threadIdx.x; b < n; b += 256) {
            int j = idx[b];
            float d = drow[j];
            float Kv = expf(-d * is2);
            float K2 = Kv * Kv;
            bool sj = j < NSRC;
            if (si && sj) {
                ss += K2;
            } else if (!si && !sj) {
                float ww = wi * wbuf[j - NSRC];
                tt += ww * ww * K2;
            } else {
                st += K2;
            }
            if (i == j) {
                if (si) trs += Kv;
                else trt += wi * wi * Kv;
            }
        }
    }
    ss = waveReduceSum(ss);
    tt = waveReduceSum(tt);
    st = waveReduceSum(st);
    trs = waveReduceSum(trs);
    trt = waveReduceSum(trt);
    __shared__ float red[4][5];
    int lane = threadIdx.x & 63, w = threadIdx.x >> 6;
    if (lane == 0) { red[w][0] = ss; red[w][1] = tt; red[w][2] = st; red[w][3] = trs; red[w][4] = trt; }
    __syncthreads();
    if (threadIdx.x < 5) {
        float v = red[0][threadIdx.x] + red[1][threadIdx.x] + red[2][threadIdx.x] + red[3][threadIdx.x];
        atomicAdd(&S[c * 5 + threadIdx.x], v);
    }
}

// ---------------- final combine ----------------
__global__ void k_final(const float* __restrict__ S,
                        const int* __restrict__ cns,
                        const int* __restrict__ cnt_,
                        const float* __restrict__ loss2,
                        float* __restrict__ out) {
    if (threadIdx.x != 0 || blockIdx.x != 0) return;
    float csum = 0.f;
    int nv = 0;
    for (int c = 0; c < NCLS; ++c) {
        float Sss = S[c * 5 + 0], Stt = S[c * 5 + 1], Sst2 = S[c * 5 + 2];
        float Tss = S[c * 5 + 3], Ttt = S[c * 5 + 4];
        float trs = Tss + EPSF, trt = Ttt + EPSF, trm = Tss + Ttt + EPSF;
        float h2s = -log2f(Sss / (trs * trs) + EPSF);
        float h2t = -log2f(Stt / (trt * trt) + EPSF);
        float h2m = -log2f((Sss + Stt + Sst2) / (trm * trm) + EPSF);
        if (cns[c] >= 2 && cnt_[c] >= 2) {
            csum += h2m - 0.5f * (h2s + h2t);
            nv++;
        }
    }
    float creda = (nv > 0) ? csum / (float)nv : 0.f;
    out[0] = loss2[0] * (1.f / 1024.f) + creda + 0.1f * (loss2[1] * (1.f / 1024.f));
}

extern "C" void kernel_launch(void* const* d_in, const int* in_sizes, int n_in,
                              void* d_out, int out_size, void* d_ws, size_t ws_size,
                              hipStream_t stream) {
    const float* fs  = (const float*)d_in[0];
    const float* ls  = (const float*)d_in[1];
    const int*   lab = (const int*)d_in[2];
    const float* ft  = (const float*)d_in[3];
    const float* lt  = (const float*)d_in[4];
    float* out = (float*)d_out;
    char* ws = (char*)d_ws;

    float*    D2      = (float*)(ws + OFF_D2);
    float*    wbuf    = (float*)(ws + OFF_WBUF);
    float*    norms   = (float*)(ws + OFF_NORMS);
    int*      clsof   = (int*)(ws + OFF_CLSOF);
    int*      cidx    = (int*)(ws + OFF_CIDX);
    int*      ccnt    = (int*)(ws + OFF_CCNT);
    int*      cns     = (int*)(ws + OFF_CNS);
    int*      cnt_    = (int*)(ws + OFF_CNT);
    float*    loss2   = (float*)(ws + OFF_LOSS2);
    unsigned* sel1    = (unsigned*)(ws + OFF_SEL1);
    unsigned* sel2    = (unsigned*)(ws + OFF_SEL2);
    unsigned* selbase = (unsigned*)(ws + OFF_SELBASE);
    float*    inv2s   = (float*)(ws + OFF_INV2S);
    float*    Ssum    = (float*)(ws + OFF_SSUM);
    unsigned* hist    = (unsigned*)(ws + OFF_HIST);
    short*    Fh      = (short*)(ws + OFF_FH);
    short*    Fl      = (short*)(ws + OFF_FL);

    // zero the counters/accumulators/histograms (ws is poisoned 0xAA each call)
    hipMemsetAsync(ws + OFF_CCNT, 0, WS_END - OFF_CCNT, stream);

    bool pre = (ws_size >= WS_END_PRE);   // constant per session -> graph-safe
    if (pre) {
        k_split<<<NTOT, 256, 0, stream>>>(fs, ft, Fh, Fl, norms);
    } else {
        k_norms<<<NTOT, 256, 0, stream>>>(fs, ft, norms);
    }
    k_rowstats<<<NTOT / 256, 256, 0, stream>>>(ls, lab, lt, wbuf, clsof, cidx, ccnt, cns, cnt_, loss2);
    if (pre) {
        k_gemm_pre<<<528, 256, 0, stream>>>(Fh, Fl, norms, D2);
    } else {
        k_gemm_d2<<<528, 256, 0, stream>>>(fs, ft, norms, D2);
    }
    k_radixpass<<<dim3(64, NCLS), 256, 0, stream>>>(D2, cidx, ccnt, clsof, hist, sel1, sel2, 1);
    k_select<<<NCLS, 256, 0, stream>>>(hist, ccnt, sel1, sel2, selbase, inv2s, 1);
    k_radixpass<<<dim3(64, NCLS), 256, 0, stream>>>(D2, cidx, ccnt, clsof, hist, sel1, sel2, 2);
    k_select<<<NCLS, 256, 0, stream>>>(hist, ccnt, sel1, sel2, selbase, inv2s, 2);
    k_radixpass<<<dim3(64, NCLS), 256, 0, stream>>>(D2, cidx, ccnt, clsof, hist, sel1, sel2, 3);
    k_select<<<NCLS, 256, 0, stream>>>(hist, ccnt, sel1, sel2, selbase, inv2s, 3);
    k_sums<<<dim3(64, NCLS), 256, 0, stream>>>(D2, cidx, ccnt, wbuf, inv2s, Ssum);
    k_final<<<1, 64, 0, stream>>>(Ssum, cns, cnt_, loss2, out);
}